// Round 15
// baseline (894.671 us; speedup 1.0000x reference)
//
#include <hip/hip_runtime.h>
#include <stdint.h>

#define NT 8192      // tokens
#define HD 2048      // hidden
#define NE 8         // experts
#define ID 1408      // inter
#define LOGIT_OFF 16777216

typedef __bf16 bf16x8 __attribute__((ext_vector_type(8)));
typedef __bf16 bf16x4 __attribute__((ext_vector_type(4)));
typedef float f32x4 __attribute__((ext_vector_type(4)));

__device__ inline bf16x8 cvt_bf8(float4 a, float4 b) {
    bf16x8 v;
    v[0] = (__bf16)a.x; v[1] = (__bf16)a.y; v[2] = (__bf16)a.z; v[3] = (__bf16)a.w;
    v[4] = (__bf16)b.x; v[5] = (__bf16)b.y; v[6] = (__bf16)b.z; v[7] = (__bf16)b.w;
    return v;
}

__device__ inline bf16x8 cvt_bf8v(f32x4 a, f32x4 b) {
    bf16x8 v;
    v[0] = (__bf16)a[0]; v[1] = (__bf16)a[1]; v[2] = (__bf16)a[2]; v[3] = (__bf16)a[3];
    v[4] = (__bf16)b[0]; v[5] = (__bf16)b[1]; v[6] = (__bf16)b[2]; v[7] = (__bf16)b[3];
    return v;
}

__device__ inline void gload16(const void* g, void* l) {
    __builtin_amdgcn_global_load_lds(
        (const __attribute__((address_space(1))) unsigned int*)g,
        (__attribute__((address_space(3))) unsigned int*)l, 16, 0, 0);
}

#define WAITV4  asm volatile("s_waitcnt vmcnt(4)" ::: "memory")
#define BARRIER do { __builtin_amdgcn_s_barrier(); asm volatile("" ::: "memory"); } while (0)
#define LGKM0   do { asm volatile("s_waitcnt lgkmcnt(0)" ::: "memory"); \
                     __builtin_amdgcn_sched_barrier(0); } while (0)

// ---------------- block-contiguous nt-load cvt: 11 chunks/thread -----------
template<int NTHR>
__device__ inline void cvt_block11(const float* __restrict__ src,
                                   __bf16* __restrict__ dst,
                                   int chunk0, int tid)
{
    f32x4 a[11], b[11];
#pragma unroll
    for (int j = 0; j < 11; ++j) {
        const f32x4* p = (const f32x4*)(src + (size_t)(chunk0 + tid + j * NTHR) * 8);
        a[j] = __builtin_nontemporal_load(p);
        b[j] = __builtin_nontemporal_load(p + 1);
    }
#pragma unroll
    for (int j = 0; j < 11; ++j)
        *(bf16x8*)(dst + (size_t)(chunk0 + tid + j * NTHR) * 8) = cvt_bf8v(a[j], b[j]);
}

// ---------------- prepA: w13 cvt (blocks 0-2047) | top2 (2048-4095) --------
__global__ __launch_bounds__(256, 2) void prepA_kernel(
    const float* __restrict__ x, const float* __restrict__ gw,
    const float* __restrict__ w13,
    float* __restrict__ logits,
    int4* __restrict__ choice, float2* __restrict__ tww,
    __bf16* __restrict__ xb, __bf16* __restrict__ w13b)
{
    const int b = blockIdx.x;
    const int tid = threadIdx.x;
    if (b < 2048) {
        cvt_block11<256>(w13, w13b, b * 2816, tid);
        return;
    }
    const int wv = tid >> 6, lane = tid & 63;
    const int t = (b - 2048) * 4 + wv;
    const f32x4* xt4 = (const f32x4*)(x + (size_t)t * HD);
    __bf16* xbt = xb + (size_t)t * HD;
    float acc[NE];
#pragma unroll
    for (int e = 0; e < NE; ++e) acc[e] = 0.f;
#pragma unroll
    for (int it = 0; it < HD / 4 / 64; ++it) {
        const int c = it * 64 + lane;
        f32x4 xv = __builtin_nontemporal_load(xt4 + c);
#pragma unroll
        for (int e = 0; e < NE; ++e) {
            f32x4 g = *((const f32x4*)(gw + e * HD) + c);
            acc[e] = fmaf(xv[0], g[0], fmaf(xv[1], g[1],
                     fmaf(xv[2], g[2], fmaf(xv[3], g[3], acc[e]))));
        }
        bf16x4 bv;
        bv[0] = (__bf16)xv[0]; bv[1] = (__bf16)xv[1];
        bv[2] = (__bf16)xv[2]; bv[3] = (__bf16)xv[3];
        *(bf16x4*)(xbt + c * 4) = bv;
    }
#pragma unroll
    for (int off = 32; off > 0; off >>= 1) {
#pragma unroll
        for (int e = 0; e < NE; ++e) acc[e] += __shfl_down(acc[e], off);
    }
    if (lane == 0) {
#pragma unroll
        for (int e = 0; e < NE; ++e) logits[(size_t)t * NE + e] = acc[e];
        int bb = 0;
#pragma unroll
        for (int e = 1; e < NE; ++e) if (acc[e] > acc[bb]) bb = e;
        int s = (bb == 0) ? 1 : 0;
#pragma unroll
        for (int e = 0; e < NE; ++e) if (e != bb && acc[e] > acc[s]) s = e;
        float er = __expf(acc[s] - acc[bb]);
        float p1 = 1.f / (1.f + er);
        float p2 = er / (1.f + er);
        choice[t] = make_int4(bb, s, 0, 0);
        tww[t] = make_float2(p1, p2);
    }
}

// ---------------- build_lists: atomic-free compaction, 1 block/expert ------
__global__ __launch_bounds__(1024) void build_lists(
    const int4* __restrict__ choice, const float2* __restrict__ tww,
    int* __restrict__ cnt, int* __restrict__ list, float* __restrict__ coef,
    int* __restrict__ pos0, int* __restrict__ pos1)
{
    const int e = blockIdx.x;
    const int tid = threadIdx.x;
    const int lane = tid & 63, w = tid >> 6;
    __shared__ int wsum[16], wbase[16];
    int4 c[8];
    int flag = 0;
    int cntt = 0;
#pragma unroll
    for (int j = 0; j < 8; ++j) {
        c[j] = choice[tid * 8 + j];
        bool f = (c[j].x == e) || (c[j].y == e);
        flag |= f ? (1 << j) : 0;
        cntt += f ? 1 : 0;
    }
    int pre = cntt;
#pragma unroll
    for (int off = 1; off < 64; off <<= 1) {
        int v = __shfl_up(pre, off);
        if (lane >= off) pre += v;
    }
    if (lane == 63) wsum[w] = pre;
    __syncthreads();
    if (tid == 0) {
        int s = 0;
        for (int i = 0; i < 16; ++i) { wbase[i] = s; s += wsum[i]; }
        cnt[e] = s;
    }
    __syncthreads();
    int base = wbase[w] + (pre - cntt);
#pragma unroll
    for (int j = 0; j < 8; ++j) {
        if (flag & (1 << j)) {
            const int t = tid * 8 + j;
            list[e * NT + base] = t;
            float2 ww = tww[t];
            if (c[j].x == e) { pos0[t] = base; coef[t * NE + e] = ww.x; }
            else             { pos1[t] = base; coef[t * NE + e] = ww.y; }
            ++base;
        }
    }
}

// ---------------- router (fallback path only, atomic version) --------------
__global__ __launch_bounds__(256) void router_kernel(
    const float* __restrict__ x, const float* __restrict__ gw,
    float* __restrict__ logits, int* __restrict__ cnt,
    int* __restrict__ list, float* __restrict__ coef)
{
    const int wv = threadIdx.x >> 6, lane = threadIdx.x & 63;
    const int t = blockIdx.x * 4 + wv;
    const float* xt = x + (size_t)t * HD;
    float acc[NE];
#pragma unroll
    for (int e = 0; e < NE; ++e) acc[e] = 0.f;
    for (int k = lane; k < HD; k += 64) {
        float xv = xt[k];
#pragma unroll
        for (int e = 0; e < NE; ++e) acc[e] = fmaf(xv, gw[e * HD + k], acc[e]);
    }
#pragma unroll
    for (int off = 32; off > 0; off >>= 1) {
#pragma unroll
        for (int e = 0; e < NE; ++e) acc[e] += __shfl_down(acc[e], off);
    }
    if (lane == 0) {
#pragma unroll
        for (int e = 0; e < NE; ++e) logits[(size_t)t * NE + e] = acc[e];
        int b = 0;
#pragma unroll
        for (int e = 1; e < NE; ++e) if (acc[e] > acc[b]) b = e;
        int s = (b == 0) ? 1 : 0;
#pragma unroll
        for (int e = 0; e < NE; ++e) if (e != b && acc[e] > acc[s]) s = e;
        float er = __expf(acc[s] - acc[b]);
        float p1 = 1.f / (1.f + er);
        float p2 = er / (1.f + er);
#pragma unroll
        for (int e = 0; e < NE; ++e) coef[t * NE + e] = 0.f;
        coef[t * NE + b] = p1;
        coef[t * NE + s] = p2;
        int pos = atomicAdd(&cnt[b], 1); list[b * NT + pos] = t;
        int pos2 = atomicAdd(&cnt[s], 1); list[s * NT + pos2] = t;
    }
}

__global__ void prefix_kernel(const int* __restrict__ cnt, int* __restrict__ prefix)
{
    if (threadIdx.x == 0) {
        int s = 0;
        for (int e = 0; e < NE; ++e) { prefix[e] = s; s += cnt[e]; }
    }
}

// ---------------- combine: out[t] = w0*P[s0] + w1*P[s1] --------------------
__global__ __launch_bounds__(256) void combine_kernel(
    const __bf16* __restrict__ partial, const int* __restrict__ prefix,
    const int4* __restrict__ choice, const float2* __restrict__ tww,
    const int* __restrict__ pos0, const int* __restrict__ pos1,
    float* __restrict__ out)
{
    const int t = blockIdx.x;
    int4 c = choice[t];
    float2 w = tww[t];
    const __bf16* p0 = partial + (size_t)(prefix[c.x] + pos0[t]) * HD;
    const __bf16* p1 = partial + (size_t)(prefix[c.y] + pos1[t]) * HD;
    float* o = out + (size_t)t * HD;
    const int cc = threadIdx.x;              // HD/8 == 256
    bf16x8 v0 = ((const bf16x8*)p0)[cc];
    bf16x8 v1 = ((const bf16x8*)p1)[cc];
    float4 r0, r1;
    r0.x = w.x * (float)v0[0] + w.y * (float)v1[0];
    r0.y = w.x * (float)v0[1] + w.y * (float)v1[1];
    r0.z = w.x * (float)v0[2] + w.y * (float)v1[2];
    r0.w = w.x * (float)v0[3] + w.y * (float)v1[3];
    r1.x = w.x * (float)v0[4] + w.y * (float)v1[4];
    r1.y = w.x * (float)v0[5] + w.y * (float)v1[5];
    r1.z = w.x * (float)v0[6] + w.y * (float)v1[6];
    r1.w = w.x * (float)v0[7] + w.y * (float)v1[7];
    ((float4*)(o + cc * 8))[0] = r0;
    ((float4*)(o + cc * 8))[1] = r1;
}

// ============ 256-tile phased bf16 kernels (R11 schedule) ==================
// R15: grid order swapped to MTILE-FASTEST. Co-resident blocks now share one
// 1.4 MB B-panel (L2/LLC-hot across its ~8 live mtiles) instead of reading 11
// different panels while sharing A (R14: FETCH 674 MB vs 217 ideal). Pure
// index permutation of the R14 best-known config -- schedule untouched.

#define SA(P_,H_) (sA + (((P_)*2 + (H_)) * 128) * 64)
#define SB(P_,H_) (sB + (((P_)*2 + (H_)) * 128) * 64)

#define STAGE_A(P_,H_,J_,K_) gload16(aS[H_][J_] + (K_), SA(P_,H_) + ((J_)*64 + wv*8) * 64)
#define STAGE_B(P_,H_,J_,K_) gload16(bS[H_][J_] + (K_), SB(P_,H_) + ((J_)*64 + wv*8) * 64)

#define READ_AF(P_,H_) do { \
    _Pragma("unroll") for (int m_ = 0; m_ < 4; ++m_) { \
        const __bf16* rp_ = SA(P_,H_) + (wm*64 + m_*16 + fr) * 64; \
        aF[m_][0] = *(const bf16x8*)(rp_ + ((fq ^ (fr&7)) * 8)); \
        aF[m_][1] = *(const bf16x8*)(rp_ + (((4+fq) ^ (fr&7)) * 8)); \
    } } while (0)

#define READ_BF(D_,P_,H_) do { \
    _Pragma("unroll") for (int n_ = 0; n_ < 2; ++n_) { \
        const __bf16* rp_ = SB(P_,H_) + (wn*32 + n_*16 + fr) * 64; \
        D_[n_][0] = *(const bf16x8*)(rp_ + ((fq ^ (fr&7)) * 8)); \
        D_[n_][1] = *(const bf16x8*)(rp_ + (((4+fq) ^ (fr&7)) * 8)); \
    } } while (0)

#define MFMA16(QM_,QH_,BF_) do { \
    __builtin_amdgcn_s_setprio(1); \
    _Pragma("unroll") for (int m_ = 0; m_ < 4; ++m_) \
    _Pragma("unroll") for (int n_ = 0; n_ < 2; ++n_) { \
        acc[QM_][QH_][m_][n_] = __builtin_amdgcn_mfma_f32_16x16x32_bf16(aF[m_][0], (BF_)[n_][0], acc[QM_][QH_][m_][n_], 0, 0, 0); \
        acc[QM_][QH_][m_][n_] = __builtin_amdgcn_mfma_f32_16x16x32_bf16(aF[m_][1], (BF_)[n_][1], acc[QM_][QH_][m_][n_], 0, 0, 0); \
    } \
    __builtin_amdgcn_s_setprio(0); \
} while (0)

#define KLOOP_PHASES(NTK_) \
    for (int t = 0; t < (NTK_); ++t) { \
        const int p = t & 1, q = p ^ 1; \
        const int kn = ((t + 1 < (NTK_)) ? (t + 1) : t) * 64; \
        READ_AF(p, 0); READ_BF(bQ0, p, 0); \
        STAGE_A(q,0,0,kn); STAGE_A(q,0,1,kn); \
        WAITV4; BARRIER; LGKM0; \
        MFMA16(0,0,bQ0); \
        READ_BF(bQ1, p, 1); \
        STAGE_B(q,0,0,kn); STAGE_B(q,0,1,kn); \
        WAITV4; BARRIER; LGKM0; \
        MFMA16(0,1,bQ1); \
        READ_AF(p, 1); \
        STAGE_B(q,1,0,kn); STAGE_B(q,1,1,kn); \
        BARRIER; LGKM0; \
        MFMA16(1,1,bQ1); \
        STAGE_A(q,1,0,kn); STAGE_A(q,1,1,kn); \
        WAITV4; BARRIER; LGKM0; \
        MFMA16(1,0,bQ0); \
    }

#define PROLOGUE_STAGE \
    STAGE_A(0,0,0,0); STAGE_A(0,0,1,0); \
    STAGE_B(0,0,0,0); STAGE_B(0,0,1,0); \
    STAGE_B(0,1,0,0); STAGE_B(0,1,1,0); \
    STAGE_A(0,1,0,0); STAGE_A(0,1,1,0); \
    WAITV4; BARRIER

// phase 1: h = silu(x@w1^T) * (x@w3^T), plus w2-cvt region.
// grid (32, 13, 8): x = mtile (fastest), y = ntile (11 GEMM + 2 cvt slots).
__global__ __launch_bounds__(512, 2) void phase1_bf16(
    const __bf16* __restrict__ xb, const __bf16* __restrict__ w13b,
    const int* __restrict__ cnt, const int* __restrict__ prefix,
    const int* __restrict__ list, __bf16* __restrict__ h,
    const float* __restrict__ w2, __bf16* __restrict__ w2b)
{
    const int ntile = blockIdx.y;
    if (ntile >= 11) {
        const int rid = (ntile - 11) + 2 * (blockIdx.x + 32 * blockIdx.z);
        cvt_block11<512>(w2, w2b, rid * 5632, threadIdx.x);
        return;
    }
    const int e = blockIdx.z;
    const int cnt_e = cnt[e];
    const int mtile = blockIdx.x;
    if (mtile * 256 >= cnt_e) return;
    const int base = prefix[e];
    const int rem = cnt_e - mtile * 256;

    extern __shared__ __bf16 smem[];
    __bf16* sA = smem;
    __bf16* sB = smem + 32768;

    const int tid = threadIdx.x;
    const int lane = tid & 63;
    const int wv = tid >> 6;
    const int wm = wv >> 2;
    const int wn = wv & 3;
    const int ri = lane >> 3;
    const int ch = lane & 7;
    const int scoff = (ch ^ ri) * 8;
    const int fr = lane & 15;
    const int fq = lane >> 4;

    const __bf16* aS[2][2];
#pragma unroll
    for (int qm = 0; qm < 2; ++qm)
#pragma unroll
        for (int j = 0; j < 2; ++j) {
            int row = qm * 128 + j * 64 + wv * 8 + ri;
            int rr = (row < rem) ? row : (rem - 1);
            int tok = list[e * NT + mtile * 256 + rr];
            aS[qm][j] = xb + (size_t)tok * HD + scoff;
        }
    const __bf16* bS[2][2];
    const size_t w13e = (size_t)e * (2 * ID);
#pragma unroll
    for (int j = 0; j < 2; ++j) {
        int row = ntile * 128 + j * 64 + wv * 8 + ri;
        bS[0][j] = w13b + (w13e + row) * HD + scoff;
        bS[1][j] = w13b + (w13e + ID + row) * HD + scoff;
    }

    f32x4 acc[2][2][4][2];
#pragma unroll
    for (int a0 = 0; a0 < 2; ++a0)
#pragma unroll
        for (int a1 = 0; a1 < 2; ++a1)
#pragma unroll
            for (int m = 0; m < 4; ++m)
#pragma unroll
                for (int n = 0; n < 2; ++n)
                    acc[a0][a1][m][n] = (f32x4){0.f, 0.f, 0.f, 0.f};

    PROLOGUE_STAGE;

    const int NTK = HD / 64;   // 32
    bf16x8 aF[4][2], bQ0[2][2], bQ1[2][2];
    KLOOP_PHASES(NTK)

    // epilogue: h = silu(g1) * g3
#pragma unroll
    for (int qm = 0; qm < 2; ++qm)
#pragma unroll
        for (int m = 0; m < 4; ++m)
#pragma unroll
            for (int j = 0; j < 4; ++j) {
                const int rl = qm * 128 + wm * 64 + m * 16 + fq * 4 + j;
                if (rl < rem) {
                    const size_t hrow = (size_t)(base + mtile * 256 + rl) * ID;
#pragma unroll
                    for (int n = 0; n < 2; ++n) {
                        float g1 = acc[qm][0][m][n][j];
                        float g3 = acc[qm][1][m][n][j];
                        float hv = g1 / (1.f + __expf(-g1)) * g3;
                        h[hrow + ntile * 128 + wn * 32 + n * 16 + fr] = (__bf16)hv;
                    }
                }
            }
}

// phase 2: P[slot] = h @ w2^T (bf16 partial stores; combined in combine_kernel).
// grid (32, 8, 8): x = mtile (fastest), y = ntile.
__global__ __launch_bounds__(512, 2) void phase2_bf16(
    const __bf16* __restrict__ h, const __bf16* __restrict__ w2b,
    const int* __restrict__ cnt, const int* __restrict__ prefix,
    const int* __restrict__ list, __bf16* __restrict__ partial)
{
    const int e = blockIdx.z;
    const int cnt_e = cnt[e];
    const int mtile = blockIdx.x;
    if (mtile * 256 >= cnt_e) return;
    const int ntile = blockIdx.y;
    const int base = prefix[e];
    const int rem = cnt_e - mtile * 256;

    extern __shared__ __bf16 smem[];
    __bf16* sA = smem;
    __bf16* sB = smem + 32768;

    const int tid = threadIdx.x;
    const int lane = tid & 63;
    const int wv = tid >> 6;
    const int wm = wv >> 2;
    const int wn = wv & 3;
    const int ri = lane >> 3;
    const int ch = lane & 7;
    const int scoff = (ch ^ ri) * 8;
    const int fr = lane & 15;
    const int fq = lane >> 4;

    const __bf16* aS[2][2];
#pragma unroll
    for (int qm = 0; qm < 2; ++qm)
#pragma unroll
        for (int j = 0; j < 2; ++j) {
            int row = qm * 128 + j * 64 + wv * 8 + ri;
            int rr = (row < rem) ? row : (rem - 1);
            aS[qm][j] = h + (size_t)(base + mtile * 256 + rr) * ID + scoff;
        }
    const __bf16* bS[2][2];
#pragma unroll
    for (int qh = 0; qh < 2; ++qh)
#pragma unroll
        for (int j = 0; j < 2; ++j) {
            int row = ntile * 256 + qh * 128 + j * 64 + wv * 8 + ri;
            bS[qh][j] = w2b + ((size_t)e * HD + row) * ID + scoff;
        }

    f32x4 acc[2][2][4][2];
#pragma unroll
    for (int a0 = 0; a0 < 2; ++a0)
#pragma unroll
        for (int a1 = 0; a1 < 2; ++a1)
#pragma unroll
            for (int m = 0; m < 4; ++m)
#pragma unroll
                for (int n = 0; n < 2; ++n)
                    acc[a0][a1][m][n] = (f32x4){0.f, 0.f, 0.f, 0.f};

    PROLOGUE_STAGE;

    const int NTK = ID / 64;   // 22
    bf16x8 aF[4][2], bQ0[2][2], bQ1[2][2];
    KLOOP_PHASES(NTK)

#pragma unroll
    for (int qm = 0; qm < 2; ++qm)
#pragma unroll
        for (int m = 0; m < 4; ++m)
#pragma unroll
            for (int j = 0; j < 4; ++j) {
                const int rl = qm * 128 + wm * 64 + m * 16 + fq * 4 + j;
                if (rl < rem) {
                    __bf16* prow = partial + (size_t)(base + mtile * 256 + rl) * HD;
#pragma unroll
                    for (int qn = 0; qn < 2; ++qn)
#pragma unroll
                        for (int n = 0; n < 2; ++n) {
                            const int col = ntile * 256 + qn * 128 + wn * 32 + n * 16 + fr;
                            prow[col] = (__bf16)acc[qm][qn][m][n][j];
                        }
                }
            }
}

// ============ fp32 fallback path (round-1, known-good) =====================
__global__ __launch_bounds__(256) void phase1_f32(
    const float* __restrict__ x, const float* __restrict__ w13,
    const int* __restrict__ cnt, const int* __restrict__ prefix,
    const int* __restrict__ list, __bf16* __restrict__ h)
{
    const int e = blockIdx.z;
    const int cnt_e = cnt[e];
    const int mtile = blockIdx.y;
    if (mtile * 128 >= cnt_e) return;
    const int ntile = blockIdx.x;
    const int base = prefix[e];
    const int rem = cnt_e - mtile * 128;

    __shared__ __align__(16) __bf16 sA[128][40];
    __shared__ __align__(16) __bf16 sB1[64][40];
    __shared__ __align__(16) __bf16 sB2[64][40];

    const int tid = threadIdx.x;
    const int lane = tid & 63;
    const int wv = tid >> 6;
    const int wr = wv >> 1;
    const int wc = wv & 1;

    const int ar = tid >> 1, ah = tid & 1;
    const int arc = (ar < rem) ? ar : (rem - 1);
    const int tok = list[e * NT + mtile * 128 + arc];
    const float* xa = x + (size_t)tok * HD + ah * 16;

    const int br = tid >> 2, bq = tid & 3;
    const float* w13e = w13 + (size_t)e * (2 * ID) * HD;
    const float* b1p = w13e + (size_t)(ntile * 64 + br) * HD + bq * 8;
    const float* b2p = w13e + (size_t)(ID + ntile * 64 + br) * HD + bq * 8;

    f32x4 acc1[4][2], acc2[4][2];
#pragma unroll
    for (int m = 0; m < 4; ++m)
#pragma unroll
        for (int n = 0; n < 2; ++n) {
            acc1[m][n] = (f32x4){0.f, 0.f, 0.f, 0.f};
            acc2[m][n] = (f32x4){0.f, 0.f, 0.f, 0.f};
        }

    const int kb = (lane >> 4) * 8;
    const int fr = lane & 15;
    const int fq = lane >> 4;

    for (int k0 = 0; k0 < HD; k0 += 32) {
        __syncthreads();
        {
            const float4* p = (const float4*)(xa + k0);
            float4 f0 = p[0], f1 = p[1], f2 = p[2], f3 = p[3];
            *(bf16x8*)&sA[ar][ah * 16] = cvt_bf8(f0, f1);
            *(bf16x8*)&sA[ar][ah * 16 + 8] = cvt_bf8(f2, f3);
        }
        {
            const float4* p = (const float4*)(b1p + k0);
            float4 f0 = p[0], f1 = p[1];
            *(bf16x8*)&sB1[br][bq * 8] = cvt_bf8(f0, f1);
        }
        {
            const float4* p = (const float4*)(b2p + k0);
            float4 f0 = p[0], f1 = p[1];
            *(bf16x8*)&sB2[br][bq * 8] = cvt_bf8(f0, f1);
        }
        __syncthreads();

        bf16x8 af[4], b1f[2], b2f[2];
#pragma unroll
        for (int m = 0; m < 4; ++m)
            af[m] = *(const bf16x8*)&sA[wr * 64 + m * 16 + fr][kb];
#pragma unroll
        for (int n = 0; n < 2; ++n) {
            b1f[n] = *(const bf16x8*)&sB1[wc * 32 + n * 16 + fr][kb];
            b2f[n] = *(const bf16x8*)&sB2[wc * 32 + n * 16 + fr][kb];
        }
#pragma unroll
        for (int m = 0; m < 4; ++m)
#pragma unroll
            for (int n = 0; n < 2; ++n) {
                acc1[m][n] = __builtin_amdgcn_mfma_f32_16x16x32_bf16(af[m], b1f[n], acc1[m][n], 0, 0, 0);
                acc2[m][n] = __builtin_amdgcn_mfma_f32_16x16x32_bf16(af[m], b2f[n], acc2[m][n], 0, 0, 0);
            }
    }

#pragma unroll
    for (int m = 0; m < 4; ++m) {
#pragma unroll
        for (int j = 0; j < 4; ++j) {
            const int rl = wr * 64 + m * 16 + fq * 4 + j;
            if (rl < rem) {
                const size_t hrow = (size_t)(base + mtile * 128 + rl) * ID;
#pragma unroll
                for (int n = 0; n < 2; ++n) {
                    float g1 = acc1[m][n][j];
                    float g2 = acc2[m][n][j];
                    float hv = g1 / (1.f + __expf(-g1)) * g2;
                    h[hrow + ntile * 64 + wc * 32 + n * 16 + fr] = (__bf16)hv;
                }
            }
        }
    }
}

__global__ __launch_bounds__(256) void phase2_f32(
    const __bf16* __restrict__ h, const float* __restrict__ w2,
    const int* __restrict__ cnt, const int* __restrict__ prefix,
    const int* __restrict__ list, const float* __restrict__ coef,
    float* __restrict__ out)
{
    const int e = blockIdx.z;
    const int cnt_e = cnt[e];
    const int mtile = blockIdx.y;
    if (mtile * 128 >= cnt_e) return;
    const int ntile = blockIdx.x;
    const int base = prefix[e];
    const int rem = cnt_e - mtile * 128;

    __shared__ __align__(16) __bf16 sA[128][40];
    __shared__ __align__(16) __bf16 sB[128][40];

    const int tid = threadIdx.x;
    const int lane = tid & 63;
    const int wv = tid >> 6;
    const int wr = wv >> 1;
    const int wc = wv & 1;

    const int ar = tid >> 1, ah = tid & 1;
    const int arc = (ar < rem) ? ar : (rem - 1);
    const __bf16* hap = h + (size_t)(base + mtile * 128 + arc) * ID + ah * 16;

    const float* w2e = w2 + (size_t)e * HD * ID;
    const float* bp = w2e + (size_t)(ntile * 128 + ar) * ID + ah * 16;

    f32x4 acc[4][4];
#pragma unroll
    for (int m = 0; m < 4; ++m)
#pragma unroll
        for (int n = 0; n < 4; ++n) acc[m][n] = (f32x4){0.f, 0.f, 0.f, 0.f};

    const int kb = (lane >> 4) * 8;
    const int fr = lane & 15;
    const int fq = lane >> 4;

    for (int k0 = 0; k0 < ID; k0 += 32) {
        __syncthreads();
        {
            const bf16x8* pa = (const bf16x8*)(hap + k0);
            *(bf16x8*)&sA[ar][ah * 16] = pa[0];
            *(bf16x8*)&sA[ar][ah * 16 + 8] = pa[1];
        }
        {
            const float4* p = (const float4*)(bp + k0);
            float4 f0 = p[0], f1 = p[1], f2 = p[2], f3 = p[3];
            *(bf16x8*)&sB[ar][ah * 16] = cvt_bf8(f0, f1);
            *(bf16x8*)&sB[ar][ah * 16 + 8] = cvt_bf8(f2, f3);
        }
        __syncthreads();

        bf16x8 af[4], bfr[4];
#pragma unroll
        for (int m = 0; m < 4; ++m)
            af[m] = *(const bf16x8*)&sA[wr * 64 + m * 16 + fr][kb];
#pragma unroll
        for (int n = 0; n < 4; ++n)
            bfr[n] = *(const bf16x8*)&sB[wc * 64 + n * 16 + fr][kb];
#pragma unroll
        for (int m = 0; m < 4; ++m)
#pragma unroll
            for (int n = 0; n < 4; ++n)
                acc[m][n] = __builtin_amdgcn_mfma_f32_16x16x32_bf16(af[m], bfr[n], acc[m][n], 0, 0, 0);
    }

#pragma unroll
    for (int m = 0; m < 4; ++m) {
#pragma unroll
        for (int j = 0; j < 4; ++j) {
            const int rl = wr * 64 + m * 16 + fq * 4 + j;
            if (rl < rem) {
                const int t = list[e * NT + mtile * 128 + rl];
                const float ce = coef[t * NE + e];
                float* orow = out + (size_t)t * HD;
#pragma unroll
                for (int n = 0; n < 4; ++n) {
                    const int col = ntile * 128 + wc * 64 + n * 16 + fr;
                    atomicAdd(&orow[col], ce * acc[m][n][j]);
                }
            }
        }
    }
}

extern "C" void kernel_launch(void* const* d_in, const int* in_sizes, int n_in,
                              void* d_out, int out_size, void* d_ws, size_t ws_size,
                              hipStream_t stream)
{
    const float* x   = (const float*)d_in[0];   // 8192 x 2048
    const float* gw  = (const float*)d_in[1];   // 8 x 2048
    const float* w13 = (const float*)d_in[2];   // 8 x 2816 x 2048
    const float* w2  = (const float*)d_in[3];   // 8 x 2048 x 1408
    float* out = (float*)d_out;                 // 16777216 out + 65536 logits

    char* ws = (char*)d_ws;
    int* cnt = (int*)ws;                                     // 32 B
    int* prefix = (int*)(ws + 32);                           // 32 B
    int* list = (int*)(ws + 64);                             // 256 KB
    float* coef = (float*)(ws + 64 + NE * NT * 4);           // 256 KB
    int4* choice = (int4*)(ws + 64 + NE * NT * 4 + NT * NE * 4);    // 128 KB
    float2* tww = (float2*)((char*)choice + NT * 16);        // 64 KB
    int* pos0 = (int*)((char*)tww + NT * 8);                 // 32 KB
    int* pos1 = pos0 + NT;                                   // 32 KB
    size_t off = ((size_t)64 + NE*NT*4 + NT*NE*4 + NT*16 + NT*8 + NT*8 + 1023) & ~(size_t)1023;

    const size_t nx = (size_t)NT * HD;            // 16.8M
    const size_t nw13 = (size_t)NE * 2 * ID * HD; // 46.1M
    const size_t nw2 = (size_t)NE * HD * ID;      // 23.1M
    const size_t nh = (size_t)2 * NT * ID;        // 23.1M
    const size_t np = (size_t)2 * NT * HD;        // 33.6M

    const size_t need_mid  = off + (nx + nw13 + nw2 + nh) * 2;
    const size_t need_full = need_mid + np * 2;

    if (ws_size >= need_full) {
        __bf16* xb   = (__bf16*)(ws + off);
        __bf16* w13b = xb + nx;
        __bf16* w2b  = w13b + nw13;
        __bf16* h    = w2b + nw2;
        __bf16* partial = h + nh;

        hipFuncSetAttribute(reinterpret_cast<const void*>(phase1_bf16),
                            hipFuncAttributeMaxDynamicSharedMemorySize, 131072);
        hipFuncSetAttribute(reinterpret_cast<const void*>(phase2_bf16),
                            hipFuncAttributeMaxDynamicSharedMemorySize, 131072);

        prepA_kernel<<<4096, 256, 0, stream>>>(x, gw, w13, out + LOGIT_OFF,
                                               choice, tww, xb, w13b);
        build_lists<<<NE, 1024, 0, stream>>>(choice, tww, cnt, list, coef, pos0, pos1);
        prefix_kernel<<<1, 64, 0, stream>>>(cnt, prefix);
        phase1_bf16<<<dim3(32, 13, NE), 512, 131072, stream>>>(
            xb, w13b, cnt, prefix, list, h, w2, w2b);
        phase2_bf16<<<dim3(32, HD / 256, NE), 512, 131072, stream>>>(
            h, w2b, cnt, prefix, list, partial);
        combine_kernel<<<NT, 256, 0, stream>>>(partial, prefix, choice, tww,
                                               pos0, pos1, out);
    } else {
        __bf16* h = (__bf16*)(ws + off);
        hipMemsetAsync(cnt, 0, 32, stream);
        hipMemsetAsync(out, 0, (size_t)LOGIT_OFF * 4, stream);
        router_kernel<<<NT / 4, 256, 0, stream>>>(x, gw, out + LOGIT_OFF, cnt, list, coef);
        prefix_kernel<<<1, 64, 0, stream>>>(cnt, prefix);
        phase1_f32<<<dim3(ID / 64, NT / 128, NE), 256, 0, stream>>>(x, w13, cnt, prefix, list, h);
        phase2_f32<<<dim3(HD / 128, NT / 128, NE), 256, 0, stream>>>(h, w2, cnt, prefix, list, coef, out);
    }
}

// Round 16
// 459.205 us; speedup vs baseline: 1.9483x; 1.9483x over previous
//
#include <hip/hip_runtime.h>
#include <stdint.h>

#define NT 8192      // tokens
#define HD 2048      // hidden
#define NE 8         // experts
#define ID 1408      // inter
#define LOGIT_OFF 16777216

typedef __bf16 bf16x8 __attribute__((ext_vector_type(8)));
typedef __bf16 bf16x4 __attribute__((ext_vector_type(4)));
typedef float f32x4 __attribute__((ext_vector_type(4)));

__device__ inline bf16x8 cvt_bf8(float4 a, float4 b) {
    bf16x8 v;
    v[0] = (__bf16)a.x; v[1] = (__bf16)a.y; v[2] = (__bf16)a.z; v[3] = (__bf16)a.w;
    v[4] = (__bf16)b.x; v[5] = (__bf16)b.y; v[6] = (__bf16)b.z; v[7] = (__bf16)b.w;
    return v;
}

__device__ inline bf16x8 cvt_bf8v(f32x4 a, f32x4 b) {
    bf16x8 v;
    v[0] = (__bf16)a[0]; v[1] = (__bf16)a[1]; v[2] = (__bf16)a[2]; v[3] = (__bf16)a[3];
    v[4] = (__bf16)b[0]; v[5] = (__bf16)b[1]; v[6] = (__bf16)b[2]; v[7] = (__bf16)b[3];
    return v;
}

__device__ inline void gload16(const void* g, void* l) {
    __builtin_amdgcn_global_load_lds(
        (const __attribute__((address_space(1))) unsigned int*)g,
        (__attribute__((address_space(3))) unsigned int*)l, 16, 0, 0);
}

#define WAITV4  asm volatile("s_waitcnt vmcnt(4)" ::: "memory")
#define BARRIER do { __builtin_amdgcn_s_barrier(); asm volatile("" ::: "memory"); } while (0)
#define LGKM0   do { asm volatile("s_waitcnt lgkmcnt(0)" ::: "memory"); \
                     __builtin_amdgcn_sched_barrier(0); } while (0)

// ---------------- block-contiguous nt-load cvt: 11 chunks/thread -----------
template<int NTHR>
__device__ inline void cvt_block11(const float* __restrict__ src,
                                   __bf16* __restrict__ dst,
                                   int chunk0, int tid)
{
    f32x4 a[11], b[11];
#pragma unroll
    for (int j = 0; j < 11; ++j) {
        const f32x4* p = (const f32x4*)(src + (size_t)(chunk0 + tid + j * NTHR) * 8);
        a[j] = __builtin_nontemporal_load(p);
        b[j] = __builtin_nontemporal_load(p + 1);
    }
#pragma unroll
    for (int j = 0; j < 11; ++j)
        *(bf16x8*)(dst + (size_t)(chunk0 + tid + j * NTHR) * 8) = cvt_bf8v(a[j], b[j]);
}

// ---------------- prepA: w13 cvt (blocks 0-2047) | top2 (2048-4095) --------
// Router region has ZERO atomics (R12: 16K same-line atomicAdds were the
// invariant ~250us tail across R4-R11).
__global__ __launch_bounds__(256, 2) void prepA_kernel(
    const float* __restrict__ x, const float* __restrict__ gw,
    const float* __restrict__ w13,
    float* __restrict__ logits,
    int4* __restrict__ choice, float2* __restrict__ tww,
    __bf16* __restrict__ xb, __bf16* __restrict__ w13b)
{
    const int b = blockIdx.x;
    const int tid = threadIdx.x;
    if (b < 2048) {
        cvt_block11<256>(w13, w13b, b * 2816, tid);
        return;
    }
    const int wv = tid >> 6, lane = tid & 63;
    const int t = (b - 2048) * 4 + wv;
    const f32x4* xt4 = (const f32x4*)(x + (size_t)t * HD);
    __bf16* xbt = xb + (size_t)t * HD;
    float acc[NE];
#pragma unroll
    for (int e = 0; e < NE; ++e) acc[e] = 0.f;
#pragma unroll
    for (int it = 0; it < HD / 4 / 64; ++it) {
        const int c = it * 64 + lane;
        f32x4 xv = __builtin_nontemporal_load(xt4 + c);
#pragma unroll
        for (int e = 0; e < NE; ++e) {
            f32x4 g = *((const f32x4*)(gw + e * HD) + c);
            acc[e] = fmaf(xv[0], g[0], fmaf(xv[1], g[1],
                     fmaf(xv[2], g[2], fmaf(xv[3], g[3], acc[e]))));
        }
        bf16x4 bv;
        bv[0] = (__bf16)xv[0]; bv[1] = (__bf16)xv[1];
        bv[2] = (__bf16)xv[2]; bv[3] = (__bf16)xv[3];
        *(bf16x4*)(xbt + c * 4) = bv;
    }
#pragma unroll
    for (int off = 32; off > 0; off >>= 1) {
#pragma unroll
        for (int e = 0; e < NE; ++e) acc[e] += __shfl_down(acc[e], off);
    }
    if (lane == 0) {
#pragma unroll
        for (int e = 0; e < NE; ++e) logits[(size_t)t * NE + e] = acc[e];
        int bb = 0;
#pragma unroll
        for (int e = 1; e < NE; ++e) if (acc[e] > acc[bb]) bb = e;
        int s = (bb == 0) ? 1 : 0;
#pragma unroll
        for (int e = 0; e < NE; ++e) if (e != bb && acc[e] > acc[s]) s = e;
        float er = __expf(acc[s] - acc[bb]);
        float p1 = 1.f / (1.f + er);
        float p2 = er / (1.f + er);
        choice[t] = make_int4(bb, s, 0, 0);
        tww[t] = make_float2(p1, p2);
    }
}

// ---------------- build_lists: atomic-free compaction, 1 block/expert ------
__global__ __launch_bounds__(1024) void build_lists(
    const int4* __restrict__ choice, const float2* __restrict__ tww,
    int* __restrict__ cnt, int* __restrict__ list, float* __restrict__ coef,
    int* __restrict__ pos0, int* __restrict__ pos1)
{
    const int e = blockIdx.x;
    const int tid = threadIdx.x;
    const int lane = tid & 63, w = tid >> 6;
    __shared__ int wsum[16], wbase[16];
    int4 c[8];
    int flag = 0;
    int cntt = 0;
#pragma unroll
    for (int j = 0; j < 8; ++j) {
        c[j] = choice[tid * 8 + j];
        bool f = (c[j].x == e) || (c[j].y == e);
        flag |= f ? (1 << j) : 0;
        cntt += f ? 1 : 0;
    }
    int pre = cntt;
#pragma unroll
    for (int off = 1; off < 64; off <<= 1) {
        int v = __shfl_up(pre, off);
        if (lane >= off) pre += v;
    }
    if (lane == 63) wsum[w] = pre;
    __syncthreads();
    if (tid == 0) {
        int s = 0;
        for (int i = 0; i < 16; ++i) { wbase[i] = s; s += wsum[i]; }
        cnt[e] = s;
    }
    __syncthreads();
    int base = wbase[w] + (pre - cntt);
#pragma unroll
    for (int j = 0; j < 8; ++j) {
        if (flag & (1 << j)) {
            const int t = tid * 8 + j;
            list[e * NT + base] = t;
            float2 ww = tww[t];
            if (c[j].x == e) { pos0[t] = base; coef[t * NE + e] = ww.x; }
            else             { pos1[t] = base; coef[t * NE + e] = ww.y; }
            ++base;
        }
    }
}

// ---------------- router (fallback path only, atomic version) --------------
__global__ __launch_bounds__(256) void router_kernel(
    const float* __restrict__ x, const float* __restrict__ gw,
    float* __restrict__ logits, int* __restrict__ cnt,
    int* __restrict__ list, float* __restrict__ coef)
{
    const int wv = threadIdx.x >> 6, lane = threadIdx.x & 63;
    const int t = blockIdx.x * 4 + wv;
    const float* xt = x + (size_t)t * HD;
    float acc[NE];
#pragma unroll
    for (int e = 0; e < NE; ++e) acc[e] = 0.f;
    for (int k = lane; k < HD; k += 64) {
        float xv = xt[k];
#pragma unroll
        for (int e = 0; e < NE; ++e) acc[e] = fmaf(xv, gw[e * HD + k], acc[e]);
    }
#pragma unroll
    for (int off = 32; off > 0; off >>= 1) {
#pragma unroll
        for (int e = 0; e < NE; ++e) acc[e] += __shfl_down(acc[e], off);
    }
    if (lane == 0) {
#pragma unroll
        for (int e = 0; e < NE; ++e) logits[(size_t)t * NE + e] = acc[e];
        int b = 0;
#pragma unroll
        for (int e = 1; e < NE; ++e) if (acc[e] > acc[b]) b = e;
        int s = (b == 0) ? 1 : 0;
#pragma unroll
        for (int e = 0; e < NE; ++e) if (e != b && acc[e] > acc[s]) s = e;
        float er = __expf(acc[s] - acc[b]);
        float p1 = 1.f / (1.f + er);
        float p2 = er / (1.f + er);
#pragma unroll
        for (int e = 0; e < NE; ++e) coef[t * NE + e] = 0.f;
        coef[t * NE + b] = p1;
        coef[t * NE + s] = p2;
        int pos = atomicAdd(&cnt[b], 1); list[b * NT + pos] = t;
        int pos2 = atomicAdd(&cnt[s], 1); list[s * NT + pos2] = t;
    }
}

__global__ void prefix_kernel(const int* __restrict__ cnt, int* __restrict__ prefix)
{
    if (threadIdx.x == 0) {
        int s = 0;
        for (int e = 0; e < NE; ++e) { prefix[e] = s; s += cnt[e]; }
    }
}

// ---------------- combine: out[t] = w0*P[s0] + w1*P[s1] --------------------
__global__ __launch_bounds__(256) void combine_kernel(
    const __bf16* __restrict__ partial, const int* __restrict__ prefix,
    const int4* __restrict__ choice, const float2* __restrict__ tww,
    const int* __restrict__ pos0, const int* __restrict__ pos1,
    float* __restrict__ out)
{
    const int t = blockIdx.x;
    int4 c = choice[t];
    float2 w = tww[t];
    const __bf16* p0 = partial + (size_t)(prefix[c.x] + pos0[t]) * HD;
    const __bf16* p1 = partial + (size_t)(prefix[c.y] + pos1[t]) * HD;
    float* o = out + (size_t)t * HD;
    const int cc = threadIdx.x;              // HD/8 == 256
    bf16x8 v0 = ((const bf16x8*)p0)[cc];
    bf16x8 v1 = ((const bf16x8*)p1)[cc];
    float4 r0, r1;
    r0.x = w.x * (float)v0[0] + w.y * (float)v1[0];
    r0.y = w.x * (float)v0[1] + w.y * (float)v1[1];
    r0.z = w.x * (float)v0[2] + w.y * (float)v1[2];
    r0.w = w.x * (float)v0[3] + w.y * (float)v1[3];
    r1.x = w.x * (float)v0[4] + w.y * (float)v1[4];
    r1.y = w.x * (float)v0[5] + w.y * (float)v1[5];
    r1.z = w.x * (float)v0[6] + w.y * (float)v1[6];
    r1.w = w.x * (float)v0[7] + w.y * (float)v1[7];
    ((float4*)(o + cc * 8))[0] = r0;
    ((float4*)(o + cc * 8))[1] = r1;
}

// ============ 256-tile phased bf16 kernels (R11 schedule, R14 grid) ========
// Grid: NTILE-FASTEST (R14). R15's mtile-fastest "panel sharing" collapsed
// machine MLP (identical miss streams dedup at L2 -> occupancy 16->6%, 2.3x
// slower). The redundant-looking B re-fetches ARE the latency hiding.

#define SA(P_,H_) (sA + (((P_)*2 + (H_)) * 128) * 64)
#define SB(P_,H_) (sB + (((P_)*2 + (H_)) * 128) * 64)

#define STAGE_A(P_,H_,J_,K_) gload16(aS[H_][J_] + (K_), SA(P_,H_) + ((J_)*64 + wv*8) * 64)
#define STAGE_B(P_,H_,J_,K_) gload16(bS[H_][J_] + (K_), SB(P_,H_) + ((J_)*64 + wv*8) * 64)

#define READ_AF(P_,H_) do { \
    _Pragma("unroll") for (int m_ = 0; m_ < 4; ++m_) { \
        const __bf16* rp_ = SA(P_,H_) + (wm*64 + m_*16 + fr) * 64; \
        aF[m_][0] = *(const bf16x8*)(rp_ + ((fq ^ (fr&7)) * 8)); \
        aF[m_][1] = *(const bf16x8*)(rp_ + (((4+fq) ^ (fr&7)) * 8)); \
    } } while (0)

#define READ_BF(D_,P_,H_) do { \
    _Pragma("unroll") for (int n_ = 0; n_ < 2; ++n_) { \
        const __bf16* rp_ = SB(P_,H_) + (wn*32 + n_*16 + fr) * 64; \
        D_[n_][0] = *(const bf16x8*)(rp_ + ((fq ^ (fr&7)) * 8)); \
        D_[n_][1] = *(const bf16x8*)(rp_ + (((4+fq) ^ (fr&7)) * 8)); \
    } } while (0)

#define MFMA16(QM_,QH_,BF_) do { \
    __builtin_amdgcn_s_setprio(1); \
    _Pragma("unroll") for (int m_ = 0; m_ < 4; ++m_) \
    _Pragma("unroll") for (int n_ = 0; n_ < 2; ++n_) { \
        acc[QM_][QH_][m_][n_] = __builtin_amdgcn_mfma_f32_16x16x32_bf16(aF[m_][0], (BF_)[n_][0], acc[QM_][QH_][m_][n_], 0, 0, 0); \
        acc[QM_][QH_][m_][n_] = __builtin_amdgcn_mfma_f32_16x16x32_bf16(aF[m_][1], (BF_)[n_][1], acc[QM_][QH_][m_][n_], 0, 0, 0); \
    } \
    __builtin_amdgcn_s_setprio(0); \
} while (0)

#define KLOOP_PHASES(NTK_) \
    for (int t = 0; t < (NTK_); ++t) { \
        const int p = t & 1, q = p ^ 1; \
        const int kn = ((t + 1 < (NTK_)) ? (t + 1) : t) * 64; \
        READ_AF(p, 0); READ_BF(bQ0, p, 0); \
        STAGE_A(q,0,0,kn); STAGE_A(q,0,1,kn); \
        WAITV4; BARRIER; LGKM0; \
        MFMA16(0,0,bQ0); \
        READ_BF(bQ1, p, 1); \
        STAGE_B(q,0,0,kn); STAGE_B(q,0,1,kn); \
        WAITV4; BARRIER; LGKM0; \
        MFMA16(0,1,bQ1); \
        READ_AF(p, 1); \
        STAGE_B(q,1,0,kn); STAGE_B(q,1,1,kn); \
        BARRIER; LGKM0; \
        MFMA16(1,1,bQ1); \
        STAGE_A(q,1,0,kn); STAGE_A(q,1,1,kn); \
        WAITV4; BARRIER; LGKM0; \
        MFMA16(1,0,bQ0); \
    }

#define PROLOGUE_STAGE \
    STAGE_A(0,0,0,0); STAGE_A(0,0,1,0); \
    STAGE_B(0,0,0,0); STAGE_B(0,0,1,0); \
    STAGE_B(0,1,0,0); STAGE_B(0,1,1,0); \
    STAGE_A(0,1,0,0); STAGE_A(0,1,1,0); \
    WAITV4; BARRIER

// phase 1: h = silu(x@w1^T) * (x@w3^T), plus w2-cvt region.
// grid (13, 32, 8): x = ntile fastest (11 GEMM + 2 cvt slots), y = mtile.
__global__ __launch_bounds__(512, 2) void phase1_bf16(
    const __bf16* __restrict__ xb, const __bf16* __restrict__ w13b,
    const int* __restrict__ cnt, const int* __restrict__ prefix,
    const int* __restrict__ list, __bf16* __restrict__ h,
    const float* __restrict__ w2, __bf16* __restrict__ w2b)
{
    const int ntile = blockIdx.x;
    if (ntile >= 11) {
        const int rid = (ntile - 11) + 2 * (blockIdx.y + 32 * blockIdx.z);
        cvt_block11<512>(w2, w2b, rid * 5632, threadIdx.x);
        return;
    }
    const int e = blockIdx.z;
    const int cnt_e = cnt[e];
    const int mtile = blockIdx.y;
    if (mtile * 256 >= cnt_e) return;
    const int base = prefix[e];
    const int rem = cnt_e - mtile * 256;

    extern __shared__ __bf16 smem[];
    __bf16* sA = smem;
    __bf16* sB = smem + 32768;

    const int tid = threadIdx.x;
    const int lane = tid & 63;
    const int wv = tid >> 6;
    const int wm = wv >> 2;
    const int wn = wv & 3;
    const int ri = lane >> 3;
    const int ch = lane & 7;
    const int scoff = (ch ^ ri) * 8;
    const int fr = lane & 15;
    const int fq = lane >> 4;

    const __bf16* aS[2][2];
#pragma unroll
    for (int qm = 0; qm < 2; ++qm)
#pragma unroll
        for (int j = 0; j < 2; ++j) {
            int row = qm * 128 + j * 64 + wv * 8 + ri;
            int rr = (row < rem) ? row : (rem - 1);
            int tok = list[e * NT + mtile * 256 + rr];
            aS[qm][j] = xb + (size_t)tok * HD + scoff;
        }
    const __bf16* bS[2][2];
    const size_t w13e = (size_t)e * (2 * ID);
#pragma unroll
    for (int j = 0; j < 2; ++j) {
        int row = ntile * 128 + j * 64 + wv * 8 + ri;
        bS[0][j] = w13b + (w13e + row) * HD + scoff;
        bS[1][j] = w13b + (w13e + ID + row) * HD + scoff;
    }

    f32x4 acc[2][2][4][2];
#pragma unroll
    for (int a0 = 0; a0 < 2; ++a0)
#pragma unroll
        for (int a1 = 0; a1 < 2; ++a1)
#pragma unroll
            for (int m = 0; m < 4; ++m)
#pragma unroll
                for (int n = 0; n < 2; ++n)
                    acc[a0][a1][m][n] = (f32x4){0.f, 0.f, 0.f, 0.f};

    PROLOGUE_STAGE;

    const int NTK = HD / 64;   // 32
    bf16x8 aF[4][2], bQ0[2][2], bQ1[2][2];
    KLOOP_PHASES(NTK)

    // epilogue: h = silu(g1) * g3
#pragma unroll
    for (int qm = 0; qm < 2; ++qm)
#pragma unroll
        for (int m = 0; m < 4; ++m)
#pragma unroll
            for (int j = 0; j < 4; ++j) {
                const int rl = qm * 128 + wm * 64 + m * 16 + fq * 4 + j;
                if (rl < rem) {
                    const size_t hrow = (size_t)(base + mtile * 256 + rl) * ID;
#pragma unroll
                    for (int n = 0; n < 2; ++n) {
                        float g1 = acc[qm][0][m][n][j];
                        float g3 = acc[qm][1][m][n][j];
                        float hv = g1 / (1.f + __expf(-g1)) * g3;
                        h[hrow + ntile * 128 + wn * 32 + n * 16 + fr] = (__bf16)hv;
                    }
                }
            }
}

// phase 2: P[slot] = h @ w2^T (bf16 partial stores; combined in combine_kernel).
// grid (8, 32, 8): x = ntile fastest, y = mtile.
__global__ __launch_bounds__(512, 2) void phase2_bf16(
    const __bf16* __restrict__ h, const __bf16* __restrict__ w2b,
    const int* __restrict__ cnt, const int* __restrict__ prefix,
    const int* __restrict__ list, __bf16* __restrict__ partial)
{
    const int e = blockIdx.z;
    const int cnt_e = cnt[e];
    const int mtile = blockIdx.y;
    if (mtile * 256 >= cnt_e) return;
    const int ntile = blockIdx.x;
    const int base = prefix[e];
    const int rem = cnt_e - mtile * 256;

    extern __shared__ __bf16 smem[];
    __bf16* sA = smem;
    __bf16* sB = smem + 32768;

    const int tid = threadIdx.x;
    const int lane = tid & 63;
    const int wv = tid >> 6;
    const int wm = wv >> 2;
    const int wn = wv & 3;
    const int ri = lane >> 3;
    const int ch = lane & 7;
    const int scoff = (ch ^ ri) * 8;
    const int fr = lane & 15;
    const int fq = lane >> 4;

    const __bf16* aS[2][2];
#pragma unroll
    for (int qm = 0; qm < 2; ++qm)
#pragma unroll
        for (int j = 0; j < 2; ++j) {
            int row = qm * 128 + j * 64 + wv * 8 + ri;
            int rr = (row < rem) ? row : (rem - 1);
            aS[qm][j] = h + (size_t)(base + mtile * 256 + rr) * ID + scoff;
        }
    const __bf16* bS[2][2];
#pragma unroll
    for (int qh = 0; qh < 2; ++qh)
#pragma unroll
        for (int j = 0; j < 2; ++j) {
            int row = ntile * 256 + qh * 128 + j * 64 + wv * 8 + ri;
            bS[qh][j] = w2b + ((size_t)e * HD + row) * ID + scoff;
        }

    f32x4 acc[2][2][4][2];
#pragma unroll
    for (int a0 = 0; a0 < 2; ++a0)
#pragma unroll
        for (int a1 = 0; a1 < 2; ++a1)
#pragma unroll
            for (int m = 0; m < 4; ++m)
#pragma unroll
                for (int n = 0; n < 2; ++n)
                    acc[a0][a1][m][n] = (f32x4){0.f, 0.f, 0.f, 0.f};

    PROLOGUE_STAGE;

    const int NTK = ID / 64;   // 22
    bf16x8 aF[4][2], bQ0[2][2], bQ1[2][2];
    KLOOP_PHASES(NTK)

#pragma unroll
    for (int qm = 0; qm < 2; ++qm)
#pragma unroll
        for (int m = 0; m < 4; ++m)
#pragma unroll
            for (int j = 0; j < 4; ++j) {
                const int rl = qm * 128 + wm * 64 + m * 16 + fq * 4 + j;
                if (rl < rem) {
                    __bf16* prow = partial + (size_t)(base + mtile * 256 + rl) * HD;
#pragma unroll
                    for (int qn = 0; qn < 2; ++qn)
#pragma unroll
                        for (int n = 0; n < 2; ++n) {
                            const int col = ntile * 256 + qn * 128 + wn * 32 + n * 16 + fr;
                            prow[col] = (__bf16)acc[qm][qn][m][n][j];
                        }
                }
            }
}

// ============ fp32 fallback path (round-1, known-good) =====================
__global__ __launch_bounds__(256) void phase1_f32(
    const float* __restrict__ x, const float* __restrict__ w13,
    const int* __restrict__ cnt, const int* __restrict__ prefix,
    const int* __restrict__ list, __bf16* __restrict__ h)
{
    const int e = blockIdx.z;
    const int cnt_e = cnt[e];
    const int mtile = blockIdx.y;
    if (mtile * 128 >= cnt_e) return;
    const int ntile = blockIdx.x;
    const int base = prefix[e];
    const int rem = cnt_e - mtile * 128;

    __shared__ __align__(16) __bf16 sA[128][40];
    __shared__ __align__(16) __bf16 sB1[64][40];
    __shared__ __align__(16) __bf16 sB2[64][40];

    const int tid = threadIdx.x;
    const int lane = tid & 63;
    const int wv = tid >> 6;
    const int wr = wv >> 1;
    const int wc = wv & 1;

    const int ar = tid >> 1, ah = tid & 1;
    const int arc = (ar < rem) ? ar : (rem - 1);
    const int tok = list[e * NT + mtile * 128 + arc];
    const float* xa = x + (size_t)tok * HD + ah * 16;

    const int br = tid >> 2, bq = tid & 3;
    const float* w13e = w13 + (size_t)e * (2 * ID) * HD;
    const float* b1p = w13e + (size_t)(ntile * 64 + br) * HD + bq * 8;
    const float* b2p = w13e + (size_t)(ID + ntile * 64 + br) * HD + bq * 8;

    f32x4 acc1[4][2], acc2[4][2];
#pragma unroll
    for (int m = 0; m < 4; ++m)
#pragma unroll
        for (int n = 0; n < 2; ++n) {
            acc1[m][n] = (f32x4){0.f, 0.f, 0.f, 0.f};
            acc2[m][n] = (f32x4){0.f, 0.f, 0.f, 0.f};
        }

    const int kb = (lane >> 4) * 8;
    const int fr = lane & 15;
    const int fq = lane >> 4;

    for (int k0 = 0; k0 < HD; k0 += 32) {
        __syncthreads();
        {
            const float4* p = (const float4*)(xa + k0);
            float4 f0 = p[0], f1 = p[1], f2 = p[2], f3 = p[3];
            *(bf16x8*)&sA[ar][ah * 16] = cvt_bf8(f0, f1);
            *(bf16x8*)&sA[ar][ah * 16 + 8] = cvt_bf8(f2, f3);
        }
        {
            const float4* p = (const float4*)(b1p + k0);
            float4 f0 = p[0], f1 = p[1];
            *(bf16x8*)&sB1[br][bq * 8] = cvt_bf8(f0, f1);
        }
        {
            const float4* p = (const float4*)(b2p + k0);
            float4 f0 = p[0], f1 = p[1];
            *(bf16x8*)&sB2[br][bq * 8] = cvt_bf8(f0, f1);
        }
        __syncthreads();

        bf16x8 af[4], b1f[2], b2f[2];
#pragma unroll
        for (int m = 0; m < 4; ++m)
            af[m] = *(const bf16x8*)&sA[wr * 64 + m * 16 + fr][kb];
#pragma unroll
        for (int n = 0; n < 2; ++n) {
            b1f[n] = *(const bf16x8*)&sB1[wc * 32 + n * 16 + fr][kb];
            b2f[n] = *(const bf16x8*)&sB2[wc * 32 + n * 16 + fr][kb];
        }
#pragma unroll
        for (int m = 0; m < 4; ++m)
#pragma unroll
            for (int n = 0; n < 2; ++n) {
                acc1[m][n] = __builtin_amdgcn_mfma_f32_16x16x32_bf16(af[m], b1f[n], acc1[m][n], 0, 0, 0);
                acc2[m][n] = __builtin_amdgcn_mfma_f32_16x16x32_bf16(af[m], b2f[n], acc2[m][n], 0, 0, 0);
            }
    }

#pragma unroll
    for (int m = 0; m < 4; ++m) {
#pragma unroll
        for (int j = 0; j < 4; ++j) {
            const int rl = wr * 64 + m * 16 + fq * 4 + j;
            if (rl < rem) {
                const size_t hrow = (size_t)(base + mtile * 128 + rl) * ID;
#pragma unroll
                for (int n = 0; n < 2; ++n) {
                    float g1 = acc1[m][n][j];
                    float g2 = acc2[m][n][j];
                    float hv = g1 / (1.f + __expf(-g1)) * g2;
                    h[hrow + ntile * 64 + wc * 32 + n * 16 + fr] = (__bf16)hv;
                }
            }
        }
    }
}

__global__ __launch_bounds__(256) void phase2_f32(
    const __bf16* __restrict__ h, const float* __restrict__ w2,
    const int* __restrict__ cnt, const int* __restrict__ prefix,
    const int* __restrict__ list, const float* __restrict__ coef,
    float* __restrict__ out)
{
    const int e = blockIdx.z;
    const int cnt_e = cnt[e];
    const int mtile = blockIdx.y;
    if (mtile * 128 >= cnt_e) return;
    const int ntile = blockIdx.x;
    const int base = prefix[e];
    const int rem = cnt_e - mtile * 128;

    __shared__ __align__(16) __bf16 sA[128][40];
    __shared__ __align__(16) __bf16 sB[128][40];

    const int tid = threadIdx.x;
    const int lane = tid & 63;
    const int wv = tid >> 6;
    const int wr = wv >> 1;
    const int wc = wv & 1;

    const int ar = tid >> 1, ah = tid & 1;
    const int arc = (ar < rem) ? ar : (rem - 1);
    const __bf16* hap = h + (size_t)(base + mtile * 128 + arc) * ID + ah * 16;

    const float* w2e = w2 + (size_t)e * HD * ID;
    const float* bp = w2e + (size_t)(ntile * 128 + ar) * ID + ah * 16;

    f32x4 acc[4][4];
#pragma unroll
    for (int m = 0; m < 4; ++m)
#pragma unroll
        for (int n = 0; n < 4; ++n) acc[m][n] = (f32x4){0.f, 0.f, 0.f, 0.f};

    const int kb = (lane >> 4) * 8;
    const int fr = lane & 15;
    const int fq = lane >> 4;

    for (int k0 = 0; k0 < ID; k0 += 32) {
        __syncthreads();
        {
            const bf16x8* pa = (const bf16x8*)(hap + k0);
            *(bf16x8*)&sA[ar][ah * 16] = pa[0];
            *(bf16x8*)&sA[ar][ah * 16 + 8] = pa[1];
        }
        {
            const float4* p = (const float4*)(bp + k0);
            float4 f0 = p[0], f1 = p[1], f2 = p[2], f3 = p[3];
            *(bf16x8*)&sB[ar][ah * 16] = cvt_bf8(f0, f1);
            *(bf16x8*)&sB[ar][ah * 16 + 8] = cvt_bf8(f2, f3);
        }
        __syncthreads();

        bf16x8 af[4], bfr[4];
#pragma unroll
        for (int m = 0; m < 4; ++m)
            af[m] = *(const bf16x8*)&sA[wr * 64 + m * 16 + fr][kb];
#pragma unroll
        for (int n = 0; n < 4; ++n)
            bfr[n] = *(const bf16x8*)&sB[wc * 64 + n * 16 + fr][kb];
#pragma unroll
        for (int m = 0; m < 4; ++m)
#pragma unroll
            for (int n = 0; n < 4; ++n)
                acc[m][n] = __builtin_amdgcn_mfma_f32_16x16x32_bf16(af[m], bfr[n], acc[m][n], 0, 0, 0);
    }

#pragma unroll
    for (int m = 0; m < 4; ++m) {
#pragma unroll
        for (int j = 0; j < 4; ++j) {
            const int rl = wr * 64 + m * 16 + fq * 4 + j;
            if (rl < rem) {
                const int t = list[e * NT + mtile * 128 + rl];
                const float ce = coef[t * NE + e];
                float* orow = out + (size_t)t * HD;
#pragma unroll
                for (int n = 0; n < 4; ++n) {
                    const int col = ntile * 128 + wc * 64 + n * 16 + fr;
                    atomicAdd(&orow[col], ce * acc[m][n][j]);
                }
            }
        }
    }
}

extern "C" void kernel_launch(void* const* d_in, const int* in_sizes, int n_in,
                              void* d_out, int out_size, void* d_ws, size_t ws_size,
                              hipStream_t stream)
{
    const float* x   = (const float*)d_in[0];   // 8192 x 2048
    const float* gw  = (const float*)d_in[1];   // 8 x 2048
    const float* w13 = (const float*)d_in[2];   // 8 x 2816 x 2048
    const float* w2  = (const float*)d_in[3];   // 8 x 2048 x 1408
    float* out = (float*)d_out;                 // 16777216 out + 65536 logits

    char* ws = (char*)d_ws;
    int* cnt = (int*)ws;                                     // 32 B
    int* prefix = (int*)(ws + 32);                           // 32 B
    int* list = (int*)(ws + 64);                             // 256 KB
    float* coef = (float*)(ws + 64 + NE * NT * 4);           // 256 KB
    int4* choice = (int4*)(ws + 64 + NE * NT * 4 + NT * NE * 4);    // 128 KB
    float2* tww = (float2*)((char*)choice + NT * 16);        // 64 KB
    int* pos0 = (int*)((char*)tww + NT * 8);                 // 32 KB
    int* pos1 = pos0 + NT;                                   // 32 KB
    size_t off = ((size_t)64 + NE*NT*4 + NT*NE*4 + NT*16 + NT*8 + NT*8 + 1023) & ~(size_t)1023;

    const size_t nx = (size_t)NT * HD;            // 16.8M
    const size_t nw13 = (size_t)NE * 2 * ID * HD; // 46.1M
    const size_t nw2 = (size_t)NE * HD * ID;      // 23.1M
    const size_t nh = (size_t)2 * NT * ID;        // 23.1M
    const size_t np = (size_t)2 * NT * HD;        // 33.6M

    const size_t need_mid  = off + (nx + nw13 + nw2 + nh) * 2;
    const size_t need_full = need_mid + np * 2;

    if (ws_size >= need_full) {
        __bf16* xb   = (__bf16*)(ws + off);
        __bf16* w13b = xb + nx;
        __bf16* w2b  = w13b + nw13;
        __bf16* h    = w2b + nw2;
        __bf16* partial = h + nh;

        hipFuncSetAttribute(reinterpret_cast<const void*>(phase1_bf16),
                            hipFuncAttributeMaxDynamicSharedMemorySize, 131072);
        hipFuncSetAttribute(reinterpret_cast<const void*>(phase2_bf16),
                            hipFuncAttributeMaxDynamicSharedMemorySize, 131072);

        prepA_kernel<<<4096, 256, 0, stream>>>(x, gw, w13, out + LOGIT_OFF,
                                               choice, tww, xb, w13b);
        build_lists<<<NE, 1024, 0, stream>>>(choice, tww, cnt, list, coef, pos0, pos1);
        prefix_kernel<<<1, 64, 0, stream>>>(cnt, prefix);
        phase1_bf16<<<dim3(13, NT / 256, NE), 512, 131072, stream>>>(
            xb, w13b, cnt, prefix, list, h, w2, w2b);
        phase2_bf16<<<dim3(HD / 256, NT / 256, NE), 512, 131072, stream>>>(
            h, w2b, cnt, prefix, list, partial);
        combine_kernel<<<NT, 256, 0, stream>>>(partial, prefix, choice, tww,
                                               pos0, pos1, out);
    } else {
        __bf16* h = (__bf16*)(ws + off);
        hipMemsetAsync(cnt, 0, 32, stream);
        hipMemsetAsync(out, 0, (size_t)LOGIT_OFF * 4, stream);
        router_kernel<<<NT / 4, 256, 0, stream>>>(x, gw, out + LOGIT_OFF, cnt, list, coef);
        prefix_kernel<<<1, 64, 0, stream>>>(cnt, prefix);
        phase1_f32<<<dim3(ID / 64, NT / 128, NE), 256, 0, stream>>>(x, w13, cnt, prefix, list, h);
        phase2_f32<<<dim3(HD / 128, NT / 128, NE), 256, 0, stream>>>(h, w2, cnt, prefix, list, coef, out);
    }
}